// Round 1
// baseline (1288.338 us; speedup 1.0000x reference)
//
#include <hip/hip_runtime.h>
#include <cstdint>

// ---------------------------------------------------------------------------
// TimeDistributedLSTM: B=32,T=128,S=32,E=256,H=256.
// N = B*T = 4096 independent sequences (state resets each outer timestep).
// Per inner step: gates[N,1024] = [x_t | h] @ [W_ih|W_hh]^T + b, then cell.
// Fused persistent kernel: 128 blocks x 32 rows, 8 waves x 512 threads.
// fp16 MFMA 16x16x32, fp32 accum + fp32 cell state (c) in VGPRs.
// ---------------------------------------------------------------------------

typedef _Float16 half8 __attribute__((ext_vector_type(8)));
typedef float f32x4 __attribute__((ext_vector_type(4)));

#define LOG2E 1.44269504088896f

#if __has_builtin(__builtin_amdgcn_exp2f)
__device__ __forceinline__ float fexp2(float x) { return __builtin_amdgcn_exp2f(x); }
#else
__device__ __forceinline__ float fexp2(float x) { return exp2f(x); }
#endif
#if __has_builtin(__builtin_amdgcn_rcpf)
__device__ __forceinline__ float frcp(float x) { return __builtin_amdgcn_rcpf(x); }
#else
__device__ __forceinline__ float frcp(float x) { return 1.0f / x; }
#endif

__device__ __forceinline__ float sigf(float z) {
    return frcp(1.0f + fexp2(-LOG2E * z));
}
__device__ __forceinline__ float tanhf_(float z) {
    // tanh(z) = 1 - 2/(exp2(2*log2e*z)+1); saturates correctly for |z| large
    return 1.0f - 2.0f * frcp(1.0f + fexp2(2.0f * LOG2E * z));
}

// ---------------------------------------------------------------------------
// Weight prep: pack Wcat = [W_ih | W_hh] (each [1024 x 256] f32, row-major,
// row = gate col g, inner = k) into fragment-ordered fp16:
//   Wf[w][kt][j][lane][jj],  w:8 waves, kt:16 k-tiles, j:8 frag streams,
//   lane:64, jj:8 halves  (1 MB total)
// Fragment (w,kt,j) is the MFMA B-operand for
//   col = (j>>1)*256 + w*32 + (j&1)*16 + (lane&15)   (gate g=j>>1, cc=j&1)
//   k   = kt*32 + (lane>>4)*8 + jj
// B[k][col] = Wcat[col][k].
// ---------------------------------------------------------------------------
__global__ void prep_wf(const float* __restrict__ Wih, const float* __restrict__ Whh,
                        _Float16* __restrict__ Wf)
{
    int idx  = blockIdx.x * 256 + threadIdx.x;   // 0..65535
    int lane = idx & 63;
    int j    = (idx >> 6) & 7;
    int kt   = (idx >> 9) & 15;
    int w    = idx >> 13;
    int col  = (j >> 1) * 256 + w * 32 + (j & 1) * 16 + (lane & 15);
    int kb   = kt * 32 + (lane >> 4) * 8;        // 8-contiguous k, never straddles 256
    const float* src = (kb < 256) ? (Wih + col * 256 + kb)
                                  : (Whh + col * 256 + (kb - 256));
    half8 hv;
#pragma unroll
    for (int jj = 0; jj < 8; ++jj) hv[jj] = (_Float16)src[jj];
    *reinterpret_cast<half8*>(Wf + (size_t)idx * 8) = hv;
}

// ---------------------------------------------------------------------------
// Main fused LSTM kernel.
// LDS A-tile (double buffered): [64 koct][32 row][8 halves] per buffer.
//   koct 0..31  = x_t   (k = e)
//   koct 32..63 = h     (k = 256 + hcol)
// Swizzle: slot = koct*32 + (row ^ (koct&7))  -> conflict-free frag reads,
// <=4-way staging writes.
// ---------------------------------------------------------------------------
__global__ __launch_bounds__(512, 2) void lstm_fused(
    const float* __restrict__ x, const _Float16* __restrict__ Wf,
    const float* __restrict__ bih, const float* __restrict__ bhh,
    float* __restrict__ out)
{
    __shared__ _Float16 Abuf[2 * 2048 * 8];   // 64 KB
    const int tid = threadIdx.x;
    const int l   = tid & 63;
    const int w   = tid >> 6;     // wave 0..7, owns h-cols [32w, 32w+32)
    const int lr  = l & 15;
    const int lk  = l >> 4;
    const int r0  = blockIdx.x * 32;

    // bias regs (b_ih + b_hh), per (gate, cc) for this lane's column
    float bias[4][2];
#pragma unroll
    for (int g = 0; g < 4; ++g)
#pragma unroll
        for (int cc = 0; cc < 2; ++cc) {
            int col = g * 256 + w * 32 + cc * 16 + lr;
            bias[g][cc] = bih[col] + bhh[col];
        }

    // prologue: stage x(t=0) into buf0 x-region, zero buf0 h-region
#pragma unroll
    for (int i = 0; i < 2; ++i) {
        int p = tid + i * 512;            // 0..1023
        int row = p >> 5, koct = p & 31;
        const float* xp = x + (((size_t)(r0 + row) * 32 + 0) * 256 + koct * 8);
        float4 v0 = reinterpret_cast<const float4*>(xp)[0];
        float4 v1 = reinterpret_cast<const float4*>(xp)[1];
        half8 hv;
        hv[0] = (_Float16)v0.x; hv[1] = (_Float16)v0.y;
        hv[2] = (_Float16)v0.z; hv[3] = (_Float16)v0.w;
        hv[4] = (_Float16)v1.x; hv[5] = (_Float16)v1.y;
        hv[6] = (_Float16)v1.z; hv[7] = (_Float16)v1.w;
        int slot = koct * 32 + (row ^ (koct & 7));
        *reinterpret_cast<half8*>(&Abuf[slot * 8]) = hv;
        // zero h region (slots 1024..2047); zero is swizzle-agnostic
        half8 z;
#pragma unroll
        for (int jj = 0; jj < 8; ++jj) z[jj] = (_Float16)0.f;
        *reinterpret_cast<half8*>(&Abuf[(1024 + p) * 8]) = z;
    }
    __syncthreads();

    // per-wave contiguous weight stream: 128 KB/step
    const _Float16* wbase = Wf + (size_t)w * (16 * 8 * 512) + l * 8;

    float cst[2][2][4];
#pragma unroll
    for (int rt = 0; rt < 2; ++rt)
#pragma unroll
        for (int cc = 0; cc < 2; ++cc)
#pragma unroll
            for (int r = 0; r < 4; ++r) cst[rt][cc][r] = 0.f;

    for (int t = 0; t < 32; ++t) {
        const int cb = t & 1;
        f32x4 acc[2][4][2];
#pragma unroll
        for (int rt = 0; rt < 2; ++rt)
#pragma unroll
            for (int g = 0; g < 4; ++g)
#pragma unroll
                for (int cc = 0; cc < 2; ++cc)
                    acc[rt][g][cc] = (f32x4){0.f, 0.f, 0.f, 0.f};

        // k-loop: 16 k-tiles of 32, register double-buffered B frags
        half8 B[2][8];
#pragma unroll
        for (int j = 0; j < 8; ++j)
            B[0][j] = *reinterpret_cast<const half8*>(wbase + (0 * 8 + j) * 512);

#pragma unroll
        for (int kt = 0; kt < 16; ++kt) {
            if (kt < 15) {
#pragma unroll
                for (int j = 0; j < 8; ++j)
                    B[(kt + 1) & 1][j] =
                        *reinterpret_cast<const half8*>(wbase + ((kt + 1) * 8 + j) * 512);
            }
            half8 a[2];
#pragma unroll
            for (int rt = 0; rt < 2; ++rt) {
                int koct = kt * 4 + lk;
                int row  = rt * 16 + lr;
                int slot = cb * 2048 + koct * 32 + (row ^ (koct & 7));
                a[rt] = *reinterpret_cast<const half8*>(&Abuf[slot * 8]);
            }
#pragma unroll
            for (int g = 0; g < 4; ++g)
#pragma unroll
                for (int cc = 0; cc < 2; ++cc)
#pragma unroll
                    for (int rt = 0; rt < 2; ++rt)
                        acc[rt][g][cc] = __builtin_amdgcn_mfma_f32_16x16x32_f16(
                            a[rt], B[kt & 1][g * 2 + cc], acc[rt][g][cc], 0, 0, 0);
        }

        // cell update (lane-local: i/f/g/o frags share (row,col) per lane)
        const int nb = cb ^ 1;
#pragma unroll
        for (int rt = 0; rt < 2; ++rt)
#pragma unroll
            for (int cc = 0; cc < 2; ++cc)
#pragma unroll
                for (int r = 0; r < 4; ++r) {
                    float zi = acc[rt][0][cc][r] + bias[0][cc];
                    float zf = acc[rt][1][cc][r] + bias[1][cc];
                    float zg = acc[rt][2][cc][r] + bias[2][cc];
                    float zo = acc[rt][3][cc][r] + bias[3][cc];
                    float ig = sigf(zi);
                    float fg = sigf(zf);
                    float gg = tanhf_(zg);
                    float og = sigf(zo);
                    float cn = fg * cst[rt][cc][r] + ig * gg;
                    cst[rt][cc][r] = cn;
                    float hv = og * tanhf_(cn);
                    int m  = rt * 16 + lk * 4 + r;
                    int hc = w * 32 + cc * 16 + lr;
                    if (t == 31) {
                        out[(size_t)(r0 + m) * 256 + hc] = hv;
                    } else {
                        int koct = 32 + (hc >> 3);
                        int slot = nb * 2048 + koct * 32 + (m ^ (koct & 7));
                        Abuf[slot * 8 + (hc & 7)] = (_Float16)hv;
                    }
                }

        // stage x for next step into the buffer we just wrote h into
        if (t < 31) {
#pragma unroll
            for (int i = 0; i < 2; ++i) {
                int p = tid + i * 512;
                int row = p >> 5, koct = p & 31;
                const float* xp =
                    x + (((size_t)(r0 + row) * 32 + (t + 1)) * 256 + koct * 8);
                float4 v0 = reinterpret_cast<const float4*>(xp)[0];
                float4 v1 = reinterpret_cast<const float4*>(xp)[1];
                half8 hv;
                hv[0] = (_Float16)v0.x; hv[1] = (_Float16)v0.y;
                hv[2] = (_Float16)v0.z; hv[3] = (_Float16)v0.w;
                hv[4] = (_Float16)v1.x; hv[5] = (_Float16)v1.y;
                hv[6] = (_Float16)v1.z; hv[7] = (_Float16)v1.w;
                int slot = nb * 2048 + koct * 32 + (row ^ (koct & 7));
                *reinterpret_cast<half8*>(&Abuf[slot * 8]) = hv;
            }
        }
        __syncthreads();
    }
}

extern "C" void kernel_launch(void* const* d_in, const int* in_sizes, int n_in,
                              void* d_out, int out_size, void* d_ws, size_t ws_size,
                              hipStream_t stream)
{
    const float* x   = (const float*)d_in[0];   // [32,128,32,256]
    const float* Wih = (const float*)d_in[1];   // [1024,256]
    const float* Whh = (const float*)d_in[2];   // [1024,256]
    const float* bih = (const float*)d_in[3];   // [1024]
    const float* bhh = (const float*)d_in[4];   // [1024]
    float* out = (float*)d_out;                 // [32,128,256]

    _Float16* Wf = (_Float16*)d_ws;             // 1 MB fragment-ordered weights

    prep_wf<<<dim3(256), dim3(256), 0, stream>>>(Wih, Whh, Wf);
    lstm_fused<<<dim3(128), dim3(512), 0, stream>>>(x, Wf, bih, bhh, out);
}

// Round 2
// 1254.470 us; speedup vs baseline: 1.0270x; 1.0270x over previous
//
#include <hip/hip_runtime.h>
#include <cstdint>

// ---------------------------------------------------------------------------
// TimeDistributedLSTM: B=32,T=128,S=32,E=256,H=256.
// N = B*T = 4096 independent sequences (state resets each outer timestep).
// Per inner step: gates[N,1024] = [x_t | h] @ [W_ih|W_hh]^T + b, then cell.
//
// R1: 128 blocks x 32 rows, 1024 threads = 16 waves, wave owns 16 h-cols.
//     Register budget cut to fit 128 VGPRs (R0 spilled: FETCH 1.86GB anomaly).
//     B-frags single-buffered; 4 waves/SIMD hides the L2 weight-stream latency.
// ---------------------------------------------------------------------------

typedef _Float16 half8 __attribute__((ext_vector_type(8)));
typedef float f32x4 __attribute__((ext_vector_type(4)));

#define LOG2E 1.44269504088896f

#if __has_builtin(__builtin_amdgcn_exp2f)
__device__ __forceinline__ float fexp2(float x) { return __builtin_amdgcn_exp2f(x); }
#else
__device__ __forceinline__ float fexp2(float x) { return exp2f(x); }
#endif
#if __has_builtin(__builtin_amdgcn_rcpf)
__device__ __forceinline__ float frcp(float x) { return __builtin_amdgcn_rcpf(x); }
#else
__device__ __forceinline__ float frcp(float x) { return 1.0f / x; }
#endif

__device__ __forceinline__ float sigf(float z) {
    return frcp(1.0f + fexp2(-LOG2E * z));
}
__device__ __forceinline__ float tanhf_(float z) {
    // tanh(z) = 1 - 2/(exp2(2*log2e*z)+1); saturates correctly for |z| large
    return 1.0f - 2.0f * frcp(1.0f + fexp2(2.0f * LOG2E * z));
}

// ---------------------------------------------------------------------------
// Weight prep: pack Wcat = [W_ih | W_hh] (each [1024 x 256] f32, row-major,
// row = gate col, inner = k) into fragment-ordered fp16 for the 16-wave split:
//   Wf[w][kt][g][lane][jj], w:16 waves, kt:16 k-tiles, g:4 gates, lane:64,
//   jj:8 halves  (1 MB total).  Fragment (w,kt,g) is the MFMA B-operand:
//   col = g*256 + w*16 + (lane&15),  k = kt*32 + (lane>>4)*8 + jj,
//   B[k][col] = Wcat[col][k].
// ---------------------------------------------------------------------------
__global__ void prep_wf(const float* __restrict__ Wih, const float* __restrict__ Whh,
                        _Float16* __restrict__ Wf)
{
    int idx  = blockIdx.x * 256 + threadIdx.x;   // 0..65535
    int lane = idx & 63;
    int g    = (idx >> 6) & 3;
    int kt   = (idx >> 8) & 15;
    int w    = idx >> 12;                        // 0..15
    int col  = g * 256 + w * 16 + (lane & 15);
    int kb   = kt * 32 + (lane >> 4) * 8;        // 8-contiguous k, never straddles 256
    const float* src = (kb < 256) ? (Wih + col * 256 + kb)
                                  : (Whh + col * 256 + (kb - 256));
    half8 hv;
#pragma unroll
    for (int jj = 0; jj < 8; ++jj) hv[jj] = (_Float16)src[jj];
    *reinterpret_cast<half8*>(Wf + (size_t)idx * 8) = hv;
}

// ---------------------------------------------------------------------------
// Main fused LSTM kernel.
// LDS A-tile (double buffered): [64 koct][32 row][8 halves] per buffer.
//   koct 0..31  = x_t (k = e),  koct 32..63 = h (k = 256 + hcol)
// Swizzle: slot = koct*32 + (row ^ (koct&7)) -> conflict-free frag reads.
// Wave w (0..15) owns h-cols [16w,16w+16) => i/f/g/o gate fragments land in
// the same lanes; cell update is lane-local; h written back to LDS.
// ---------------------------------------------------------------------------
__global__ __launch_bounds__(1024, 4) void lstm_fused(
    const float* __restrict__ x, const _Float16* __restrict__ Wf,
    const float* __restrict__ bih, const float* __restrict__ bhh,
    float* __restrict__ out)
{
    __shared__ _Float16 Abuf[2 * 2048 * 8];   // 64 KB
    const int tid = threadIdx.x;
    const int l   = tid & 63;
    const int w   = tid >> 6;     // wave 0..15, owns h-cols [16w, 16w+16)
    const int lr  = l & 15;
    const int lk  = l >> 4;
    const int r0  = blockIdx.x * 32;

    // bias regs (b_ih + b_hh) for this lane's gate columns
    float bias[4];
#pragma unroll
    for (int g = 0; g < 4; ++g) {
        int col = g * 256 + w * 16 + lr;
        bias[g] = bih[col] + bhh[col];
    }

    // prologue: stage x(t=0) into buf0 x-region, zero buf0 h-region
    {
        int p = tid;                      // 0..1023
        int row = p >> 5, koct = p & 31;
        const float* xp = x + (((size_t)(r0 + row) * 32 + 0) * 256 + koct * 8);
        float4 v0 = reinterpret_cast<const float4*>(xp)[0];
        float4 v1 = reinterpret_cast<const float4*>(xp)[1];
        half8 hv;
        hv[0] = (_Float16)v0.x; hv[1] = (_Float16)v0.y;
        hv[2] = (_Float16)v0.z; hv[3] = (_Float16)v0.w;
        hv[4] = (_Float16)v1.x; hv[5] = (_Float16)v1.y;
        hv[6] = (_Float16)v1.z; hv[7] = (_Float16)v1.w;
        int slot = koct * 32 + (row ^ (koct & 7));
        *reinterpret_cast<half8*>(&Abuf[slot * 8]) = hv;
        half8 z;
#pragma unroll
        for (int jj = 0; jj < 8; ++jj) z[jj] = (_Float16)0.f;
        *reinterpret_cast<half8*>(&Abuf[(1024 + p) * 8]) = z;   // zero h region
    }
    __syncthreads();

    // per-wave contiguous weight stream: 64 KB/step
    const _Float16* wbase = Wf + (size_t)w * 32768 + (size_t)l * 8;

    float cst[2][4];
#pragma unroll
    for (int rt = 0; rt < 2; ++rt)
#pragma unroll
        for (int r = 0; r < 4; ++r) cst[rt][r] = 0.f;

    for (int t = 0; t < 32; ++t) {
        const int cb = t & 1;
        const int nb = cb ^ 1;

        f32x4 acc[2][4];
#pragma unroll
        for (int rt = 0; rt < 2; ++rt)
#pragma unroll
            for (int g = 0; g < 4; ++g)
                acc[rt][g] = (f32x4){bias[g], bias[g], bias[g], bias[g]};

        // k-loop: 16 k-tiles of 32; B single-buffered (TLP hides L2 latency)
#pragma unroll
        for (int kt = 0; kt < 16; ++kt) {
            half8 Bf[4];
#pragma unroll
            for (int g = 0; g < 4; ++g)
                Bf[g] = *reinterpret_cast<const half8*>(wbase + (size_t)(kt * 4 + g) * 512);
            half8 a[2];
#pragma unroll
            for (int rt = 0; rt < 2; ++rt) {
                int koct = kt * 4 + lk;
                int row  = rt * 16 + lr;
                int slot = cb * 2048 + koct * 32 + (row ^ (koct & 7));
                a[rt] = *reinterpret_cast<const half8*>(&Abuf[slot * 8]);
            }
#pragma unroll
            for (int g = 0; g < 4; ++g)
#pragma unroll
                for (int rt = 0; rt < 2; ++rt)
                    acc[rt][g] = __builtin_amdgcn_mfma_f32_16x16x32_f16(
                        a[rt], Bf[g], acc[rt][g], 0, 0, 0);
        }

        // cell update (lane-local: i/f/g/o frags share (row,col) per lane)
#pragma unroll
        for (int rt = 0; rt < 2; ++rt)
#pragma unroll
            for (int r = 0; r < 4; ++r) {
                float zi = acc[rt][0][r];
                float zf = acc[rt][1][r];
                float zg = acc[rt][2][r];
                float zo = acc[rt][3][r];
                float ig = sigf(zi);
                float fg = sigf(zf);
                float gg = tanhf_(zg);
                float og = sigf(zo);
                float cn = fg * cst[rt][r] + ig * gg;
                cst[rt][r] = cn;
                float hv = og * tanhf_(cn);
                int m  = rt * 16 + lk * 4 + r;
                int hc = w * 16 + lr;
                if (t == 31) {
                    out[(size_t)(r0 + m) * 256 + hc] = hv;
                } else {
                    int koct = 32 + (hc >> 3);
                    int slot = nb * 2048 + koct * 32 + (m ^ (koct & 7));
                    Abuf[slot * 8 + (hc & 7)] = (_Float16)hv;
                }
            }

        // stage x for next step into the buffer we just wrote h into
        if (t < 31) {
            int p = tid;
            int row = p >> 5, koct = p & 31;
            const float* xp =
                x + (((size_t)(r0 + row) * 32 + (t + 1)) * 256 + koct * 8);
            float4 v0 = reinterpret_cast<const float4*>(xp)[0];
            float4 v1 = reinterpret_cast<const float4*>(xp)[1];
            half8 hv;
            hv[0] = (_Float16)v0.x; hv[1] = (_Float16)v0.y;
            hv[2] = (_Float16)v0.z; hv[3] = (_Float16)v0.w;
            hv[4] = (_Float16)v1.x; hv[5] = (_Float16)v1.y;
            hv[6] = (_Float16)v1.z; hv[7] = (_Float16)v1.w;
            int slot = nb * 2048 + koct * 32 + (row ^ (koct & 7));
            *reinterpret_cast<half8*>(&Abuf[slot * 8]) = hv;
        }
        __syncthreads();
    }
}

extern "C" void kernel_launch(void* const* d_in, const int* in_sizes, int n_in,
                              void* d_out, int out_size, void* d_ws, size_t ws_size,
                              hipStream_t stream)
{
    const float* x   = (const float*)d_in[0];   // [32,128,32,256]
    const float* Wih = (const float*)d_in[1];   // [1024,256]
    const float* Whh = (const float*)d_in[2];   // [1024,256]
    const float* bih = (const float*)d_in[3];   // [1024]
    const float* bhh = (const float*)d_in[4];   // [1024]
    float* out = (float*)d_out;                 // [32,128,256]

    _Float16* Wf = (_Float16*)d_ws;             // 1 MB fragment-ordered weights

    prep_wf<<<dim3(256), dim3(256), 0, stream>>>(Wih, Whh, Wf);
    lstm_fused<<<dim3(128), dim3(1024), 0, stream>>>(x, Wf, bih, bhh, out);
}

// Round 3
// 513.732 us; speedup vs baseline: 2.5078x; 2.4419x over previous
//
#include <hip/hip_runtime.h>
#include <cstdint>

// ---------------------------------------------------------------------------
// TimeDistributedLSTM: B=32,T=128,S=32,E=256,H=256.
// N = B*T = 4096 independent sequences (state resets each outer timestep).
// Per inner step: gates[N,1024] = [x_t | h] @ [W_ih|W_hh]^T + b, then cell.
//
// R2: identical structure to R1 (128 blocks x 32 rows, 16 waves, wave owns
//     16 h-cols) with the spill fix: __launch_bounds__ second arg behaves as
//     min BLOCKS/CU on this toolchain (R0: (512,2)->128 VGPR, R1: (1024,4)->64
//     VGPR — both match blocks-semantics). (1024,1) -> 128 VGPR cap, fits the
//     ~90-reg live set spill-free. unroll 4 on k-loop bounds load hoisting.
// ---------------------------------------------------------------------------

typedef _Float16 half8 __attribute__((ext_vector_type(8)));
typedef float f32x4 __attribute__((ext_vector_type(4)));

#define LOG2E 1.44269504088896f

#if __has_builtin(__builtin_amdgcn_exp2f)
__device__ __forceinline__ float fexp2(float x) { return __builtin_amdgcn_exp2f(x); }
#else
__device__ __forceinline__ float fexp2(float x) { return exp2f(x); }
#endif
#if __has_builtin(__builtin_amdgcn_rcpf)
__device__ __forceinline__ float frcp(float x) { return __builtin_amdgcn_rcpf(x); }
#else
__device__ __forceinline__ float frcp(float x) { return 1.0f / x; }
#endif

__device__ __forceinline__ float sigf(float z) {
    return frcp(1.0f + fexp2(-LOG2E * z));
}
__device__ __forceinline__ float tanhf_(float z) {
    // tanh(z) = 1 - 2/(exp2(2*log2e*z)+1); saturates correctly for |z| large
    return 1.0f - 2.0f * frcp(1.0f + fexp2(2.0f * LOG2E * z));
}

// ---------------------------------------------------------------------------
// Weight prep: pack Wcat = [W_ih | W_hh] (each [1024 x 256] f32, row-major,
// row = gate col, inner = k) into fragment-ordered fp16 for the 16-wave split:
//   Wf[w][kt][g][lane][jj], w:16 waves, kt:16 k-tiles, g:4 gates, lane:64,
//   jj:8 halves  (1 MB total).  Fragment (w,kt,g) is the MFMA B-operand:
//   col = g*256 + w*16 + (lane&15),  k = kt*32 + (lane>>4)*8 + jj,
//   B[k][col] = Wcat[col][k].
// ---------------------------------------------------------------------------
__global__ void prep_wf(const float* __restrict__ Wih, const float* __restrict__ Whh,
                        _Float16* __restrict__ Wf)
{
    int idx  = blockIdx.x * 256 + threadIdx.x;   // 0..65535
    int lane = idx & 63;
    int g    = (idx >> 6) & 3;
    int kt   = (idx >> 8) & 15;
    int w    = idx >> 12;                        // 0..15
    int col  = g * 256 + w * 16 + (lane & 15);
    int kb   = kt * 32 + (lane >> 4) * 8;        // 8-contiguous k, never straddles 256
    const float* src = (kb < 256) ? (Wih + col * 256 + kb)
                                  : (Whh + col * 256 + (kb - 256));
    half8 hv;
#pragma unroll
    for (int jj = 0; jj < 8; ++jj) hv[jj] = (_Float16)src[jj];
    *reinterpret_cast<half8*>(Wf + (size_t)idx * 8) = hv;
}

// ---------------------------------------------------------------------------
// Main fused LSTM kernel.
// LDS A-tile (double buffered): [64 koct][32 row][8 halves] per buffer.
//   koct 0..31  = x_t (k = e),  koct 32..63 = h (k = 256 + hcol)
// Swizzle: slot = koct*32 + (row ^ (koct&7)) -> conflict-free frag reads.
// Wave w (0..15) owns h-cols [16w,16w+16) => i/f/g/o gate fragments land in
// the same lanes; cell update is lane-local; h written back to LDS.
// ---------------------------------------------------------------------------
__global__ __launch_bounds__(1024, 1) void lstm_fused(
    const float* __restrict__ x, const _Float16* __restrict__ Wf,
    const float* __restrict__ bih, const float* __restrict__ bhh,
    float* __restrict__ out)
{
    __shared__ _Float16 Abuf[2 * 2048 * 8];   // 64 KB
    const int tid = threadIdx.x;
    const int l   = tid & 63;
    const int w   = tid >> 6;     // wave 0..15, owns h-cols [16w, 16w+16)
    const int lr  = l & 15;
    const int lk  = l >> 4;
    const int r0  = blockIdx.x * 32;

    // bias regs (b_ih + b_hh) for this lane's gate columns
    float bias[4];
#pragma unroll
    for (int g = 0; g < 4; ++g) {
        int col = g * 256 + w * 16 + lr;
        bias[g] = bih[col] + bhh[col];
    }

    // prologue: stage x(t=0) into buf0 x-region, zero buf0 h-region
    {
        int p = tid;                      // 0..1023
        int row = p >> 5, koct = p & 31;
        const float* xp = x + (((size_t)(r0 + row) * 32 + 0) * 256 + koct * 8);
        float4 v0 = reinterpret_cast<const float4*>(xp)[0];
        float4 v1 = reinterpret_cast<const float4*>(xp)[1];
        half8 hv;
        hv[0] = (_Float16)v0.x; hv[1] = (_Float16)v0.y;
        hv[2] = (_Float16)v0.z; hv[3] = (_Float16)v0.w;
        hv[4] = (_Float16)v1.x; hv[5] = (_Float16)v1.y;
        hv[6] = (_Float16)v1.z; hv[7] = (_Float16)v1.w;
        int slot = koct * 32 + (row ^ (koct & 7));
        *reinterpret_cast<half8*>(&Abuf[slot * 8]) = hv;
        half8 z;
#pragma unroll
        for (int jj = 0; jj < 8; ++jj) z[jj] = (_Float16)0.f;
        *reinterpret_cast<half8*>(&Abuf[(1024 + p) * 8]) = z;   // zero h region
    }
    __syncthreads();

    // per-wave contiguous weight stream: 64 KB/step
    const _Float16* wbase = Wf + (size_t)w * 32768 + (size_t)l * 8;

    float cst[2][4];
#pragma unroll
    for (int rt = 0; rt < 2; ++rt)
#pragma unroll
        for (int r = 0; r < 4; ++r) cst[rt][r] = 0.f;

    for (int t = 0; t < 32; ++t) {
        const int cb = t & 1;
        const int nb = cb ^ 1;

        f32x4 acc[2][4];
#pragma unroll
        for (int rt = 0; rt < 2; ++rt)
#pragma unroll
            for (int g = 0; g < 4; ++g)
                acc[rt][g] = (f32x4){bias[g], bias[g], bias[g], bias[g]};

        // k-loop: 16 k-tiles of 32; B single-buffered (TLP hides L2 latency).
        // unroll 4: bounds the scheduler's load hoisting so live regs stay <128.
#pragma unroll 4
        for (int kt = 0; kt < 16; ++kt) {
            half8 Bf[4];
#pragma unroll
            for (int g = 0; g < 4; ++g)
                Bf[g] = *reinterpret_cast<const half8*>(wbase + (size_t)(kt * 4 + g) * 512);
            half8 a[2];
#pragma unroll
            for (int rt = 0; rt < 2; ++rt) {
                int koct = kt * 4 + lk;
                int row  = rt * 16 + lr;
                int slot = cb * 2048 + koct * 32 + (row ^ (koct & 7));
                a[rt] = *reinterpret_cast<const half8*>(&Abuf[slot * 8]);
            }
#pragma unroll
            for (int g = 0; g < 4; ++g)
#pragma unroll
                for (int rt = 0; rt < 2; ++rt)
                    acc[rt][g] = __builtin_amdgcn_mfma_f32_16x16x32_f16(
                        a[rt], Bf[g], acc[rt][g], 0, 0, 0);
        }

        // cell update (lane-local: i/f/g/o frags share (row,col) per lane)
#pragma unroll
        for (int rt = 0; rt < 2; ++rt)
#pragma unroll
            for (int r = 0; r < 4; ++r) {
                float zi = acc[rt][0][r];
                float zf = acc[rt][1][r];
                float zg = acc[rt][2][r];
                float zo = acc[rt][3][r];
                float ig = sigf(zi);
                float fg = sigf(zf);
                float gg = tanhf_(zg);
                float og = sigf(zo);
                float cn = fg * cst[rt][r] + ig * gg;
                cst[rt][r] = cn;
                float hv = og * tanhf_(cn);
                int m  = rt * 16 + lk * 4 + r;
                int hc = w * 16 + lr;
                if (t == 31) {
                    out[(size_t)(r0 + m) * 256 + hc] = hv;
                } else {
                    int koct = 32 + (hc >> 3);
                    int slot = nb * 2048 + koct * 32 + (m ^ (koct & 7));
                    Abuf[slot * 8 + (hc & 7)] = (_Float16)hv;
                }
            }

        // stage x for next step into the buffer we just wrote h into
        if (t < 31) {
            int p = tid;
            int row = p >> 5, koct = p & 31;
            const float* xp =
                x + (((size_t)(r0 + row) * 32 + (t + 1)) * 256 + koct * 8);
            float4 v0 = reinterpret_cast<const float4*>(xp)[0];
            float4 v1 = reinterpret_cast<const float4*>(xp)[1];
            half8 hv;
            hv[0] = (_Float16)v0.x; hv[1] = (_Float16)v0.y;
            hv[2] = (_Float16)v0.z; hv[3] = (_Float16)v0.w;
            hv[4] = (_Float16)v1.x; hv[5] = (_Float16)v1.y;
            hv[6] = (_Float16)v1.z; hv[7] = (_Float16)v1.w;
            int slot = nb * 2048 + koct * 32 + (row ^ (koct & 7));
            *reinterpret_cast<half8*>(&Abuf[slot * 8]) = hv;
        }
        __syncthreads();
    }
}

extern "C" void kernel_launch(void* const* d_in, const int* in_sizes, int n_in,
                              void* d_out, int out_size, void* d_ws, size_t ws_size,
                              hipStream_t stream)
{
    const float* x   = (const float*)d_in[0];   // [32,128,32,256]
    const float* Wih = (const float*)d_in[1];   // [1024,256]
    const float* Whh = (const float*)d_in[2];   // [1024,256]
    const float* bih = (const float*)d_in[3];   // [1024]
    const float* bhh = (const float*)d_in[4];   // [1024]
    float* out = (float*)d_out;                 // [32,128,256]

    _Float16* Wf = (_Float16*)d_ws;             // 1 MB fragment-ordered weights

    prep_wf<<<dim3(256), dim3(256), 0, stream>>>(Wih, Whh, Wf);
    lstm_fused<<<dim3(128), dim3(1024), 0, stream>>>(x, Wf, bih, bhh, out);
}